// Round 5
// baseline (589.976 us; speedup 1.0000x reference)
//
#include <hip/hip_runtime.h>

typedef __attribute__((ext_vector_type(8))) _Float16 half8;
typedef __attribute__((ext_vector_type(4))) float f32x4;

#define N1_ 100000
#define N2_ 200000
#define N3_ 300000
#define N4_ 400000

typedef __attribute__((address_space(1))) const void gconst_t;
typedef __attribute__((address_space(3))) void lds_t;

__device__ __forceinline__ unsigned short f2h_bits(float x) {
  union { _Float16 h; unsigned short u; } cv;
  cv.h = (_Float16)x;
  return cv.u;
}

__device__ __forceinline__ f32x4 mfma16(half8 a, half8 b, f32x4 c) {
  return __builtin_amdgcn_mfma_f32_16x16x32_f16(a, b, c, 0, 0, 0);
}

// ---- convert h (fp32) -> fp16 bits --------------------------------------
__global__ void cvt_h_kernel(const float* __restrict__ h,
                             unsigned short* __restrict__ hf, int n4) {
  int i = blockIdx.x * blockDim.x + threadIdx.x;
  if (i >= n4) return;
  float4 v = reinterpret_cast<const float4*>(h)[i];
  ushort4 o;
  o.x = f2h_bits(v.x); o.y = f2h_bits(v.y);
  o.z = f2h_bits(v.z); o.w = f2h_bits(v.w);
  reinterpret_cast<ushort4*>(hf)[i] = o;
}

// ---- pack weights into MFMA B-fragment order ----------------------------
// packed[kt*4096 + nt*512 + lane*8 + j] = W[kt*32 + (lane>>4)*8 + j][nt*16 + (lane&15)]
struct PackInfo {
  const float* W[12];
  int kt_base[13];
  int out_off[12];
};

__global__ void pack_w_kernel(PackInfo info, unsigned short* __restrict__ pw) {
  int b = blockIdx.x;
  int lane = threadIdx.x;  // 64 threads
  int m = 0;
  while (m < 11 && b >= info.kt_base[m + 1]) ++m;
  int kt = b - info.kt_base[m];
  const float* W = info.W[m];
  int lr = lane & 15, kb = lane >> 4;
  unsigned short* outp = pw + info.out_off[m] + (size_t)kt * 4096 + lane * 8;
  #pragma unroll
  for (int nt = 0; nt < 8; ++nt) {
    #pragma unroll
    for (int j = 0; j < 8; ++j) {
      int krow = kt * 32 + kb * 8 + j;
      int col = nt * 16 + lr;
      outp[nt * 512 + j] = f2h_bits(W[(size_t)krow * 128 + col]);
    }
  }
}

// ---- main level kernel --------------------------------------------------
// 8 waves/block x ONE 16-row tile each (128 rows/block). 2-phase staged
// weight slabs (8 KB, each wave DMAs 1 KB). Paired-gather layer-0 stream:
// pairs {(sp,sub),(K-1-sp,sub)} share one gathered fragment pair across
// both directions of both phases. 16 waves/CU target (VGPR<=128, LDS 80KB).
template <int K, int NHEAD>
__global__ __launch_bounds__(512, 4) void level_kernel(
    const unsigned short* __restrict__ hf,
    const int* __restrict__ idx,
    const unsigned short* __restrict__ pw,  // packed W0|W1|W2 (fp16 bits)
    const float* __restrict__ b0, const float* __restrict__ b1,
    const float* __restrict__ b2,
    const float* __restrict__ hw0, const float* __restrict__ hb0,
    float* __restrict__ out0,
    const float* __restrict__ hw1, const float* __restrict__ hb1,
    float* __restrict__ out1,
    const float* __restrict__ hw2, const float* __restrict__ hb2,
    float* __restrict__ out2,
    int N) {
  constexpr int NDIR = (K > 1) ? 2 : 1;
  constexpr int KT0 = 4 * K;
  constexpr int NPAIR = (K / 2) * 4;   // paired phases = 2*NPAIR
  constexpr bool MID = (K % 2) != 0;   // middle seg (odd K, incl. K==1)

  __shared__ __align__(16) unsigned short bstage[2][4096];     // 16 KB
  __shared__ __align__(16) unsigned short act[8][NDIR][2048];  // 32/64 KB

  const int lane = threadIdx.x & 63;
  const int wid = threadIdx.x >> 6;   // 0..7
  const int lrow = lane & 15;
  const int kb = lane >> 4;

  int tile = blockIdx.x * 8 + wid;
  const int maxtile = N / 16 - 1;
  const bool wr = (tile <= maxtile);
  if (!wr) tile = maxtile;  // clamp: all waves hit barriers, only writers store

  int src[K];
  #pragma unroll
  for (int s = 0; s < K; ++s)
    src[s] = (K == 1) ? (tile * 16 + lrow)
                      : idx[(size_t)(tile * 16 + lrow) * K + s];

  // stage one 8 KB slab into bstage[buf]; each wave DMAs 1 KB, width-16
  auto stage = [&](int buf, const unsigned short* slab) {
    const unsigned short* g = slab + wid * 512 + lane * 8;
    unsigned short* l = &bstage[buf][wid * 512];
    __builtin_amdgcn_global_load_lds((gconst_t*)g, (lds_t*)l, 16, 0, 0);
  };

  // gathered fragment for (segRow, sub): 16B/lane from h-row src[segRow]
  auto gfrag = [&](int segRow, int sub, half8& dst) {
    dst = *reinterpret_cast<const half8*>(
        hf + (size_t)src[segRow] * 128 + sub * 32 + kb * 8);
  };

  f32x4 acc[NDIR][8];
  auto zero_acc = [&]() {
    #pragma unroll
    for (int d = 0; d < NDIR; ++d)
      #pragma unroll
      for (int nt = 0; nt < 8; ++nt) acc[d][nt] = f32x4{0.f, 0.f, 0.f, 0.f};
  };

  // one slab's MFMAs: acc[0] uses af, acc[1] uses ab (weights in bstage[buf])
  auto mfma_phase = [&](int buf, half8 af, half8 ab) {
    #pragma unroll
    for (int nt = 0; nt < 8; ++nt) {
      half8 bq = *reinterpret_cast<const half8*>(&bstage[buf][nt * 512 + lane * 8]);
      acc[0][nt] = mfma16(af, bq, acc[0][nt]);
      if constexpr (NDIR == 2) acc[1][nt] = mfma16(ab, bq, acc[1][nt]);
    }
  };

  // layers 1/2: A from per-wave activation LDS (XOR-swizzled rows)
  auto actA = [&](int d, int kt) -> half8 {
    unsigned off = (unsigned)(lrow * 256 + (kt * 32 + kb * 8) * 2) ^
                   ((unsigned)(lrow & 7) << 4);
    return *reinterpret_cast<const half8*>(
        reinterpret_cast<const unsigned char*>(&act[wid][d][0]) + off);
  };

  // bias + relu + fp16 store to swizzled act LDS (D-frag: row=4*kb+r, col=nt*16+lrow)
  auto store_act = [&](int d, const float* bias) {
    unsigned char* base = reinterpret_cast<unsigned char*>(&act[wid][d][0]);
    #pragma unroll
    for (int nt = 0; nt < 8; ++nt) {
      float bv = bias[nt * 16 + lrow];
      #pragma unroll
      for (int r = 0; r < 4; ++r) {
        float v = fmaxf(acc[d][nt][r] + bv, 0.f);
        int trow = 4 * kb + r;
        unsigned off = (unsigned)(trow * 256 + (nt * 16 + lrow) * 2) ^
                       ((unsigned)(trow & 7) << 4);
        *reinterpret_cast<unsigned short*>(base + off) = f2h_bits(v);
      }
    }
  };

  int cur = 0;
  zero_acc();

  // ================= layer 0: paired-gather slab stream ===================
  half8 gA, gB, nA, nB;
  stage(cur, pw);        // first slab: pair0 slabA, or mid slab 0 (K==1)
  gfrag(0, 0, gA);
  if constexpr (NPAIR > 0) gfrag(K - 1, 0, gB);
  __syncthreads();

  for (int pr = 0; pr < NPAIR; ++pr) {
    const int sp = pr >> 2, sub = pr & 3;
    const int slabB = (K - 1 - sp) * 4 + sub;
    // -- phase 1: weights slab (sp,sub): fwd uses gA, bwd uses gB
    stage(cur ^ 1, pw + (size_t)slabB * 4096);
    mfma_phase(cur, gA, gB);
    __syncthreads();
    cur ^= 1;
    // -- phase 2: weights slab (K-1-sp,sub): fwd uses gB, bwd uses gA
    if (pr + 1 < NPAIR) {
      const int sp2 = (pr + 1) >> 2, sub2 = (pr + 1) & 3;
      stage(cur ^ 1, pw + (size_t)(sp2 * 4 + sub2) * 4096);
      gfrag(sp2, sub2, nA);
      gfrag(K - 1 - sp2, sub2, nB);
    } else if constexpr (MID) {
      stage(cur ^ 1, pw + (size_t)(((K - 1) / 2) * 4) * 4096);
      gfrag((K - 1) / 2, 0, nA);
    } else {
      stage(cur ^ 1, pw + (size_t)KT0 * 4096);  // layer-1 slab 0
    }
    mfma_phase(cur, gB, gA);
    __syncthreads();
    cur ^= 1;
    gA = nA; gB = nB;
  }

  if constexpr (MID) {
    const int mseg = (K - 1) / 2;
    for (int sub = 0; sub < 4; ++sub) {
      if (sub + 1 < 4) {
        stage(cur ^ 1, pw + (size_t)(mseg * 4 + sub + 1) * 4096);
        gfrag(mseg, sub + 1, nA);
      } else {
        stage(cur ^ 1, pw + (size_t)KT0 * 4096);  // layer-1 slab 0
      }
      mfma_phase(cur, gA, gA);  // fwd and bwd share the middle fragment
      __syncthreads();
      cur ^= 1;
      gA = nA;
    }
  }

  #pragma unroll
  for (int d = 0; d < NDIR; ++d) store_act(d, b0);

  // ================= layers 1 and 2 (A from act LDS) =====================
  const unsigned short* w1 = pw + (size_t)KT0 * 4096;
  #pragma unroll 1
  for (int layer = 1; layer <= 2; ++layer) {
    const unsigned short* w = (layer == 1) ? w1 : w1 + 16384;
    zero_acc();
    for (int kt = 0; kt < 4; ++kt) {
      if (kt + 1 < 4) stage(cur ^ 1, w + (size_t)(kt + 1) * 4096);
      else if (layer == 1) stage(cur ^ 1, w1 + 16384);  // layer-2 slab 0
      half8 a[NDIR];
      #pragma unroll
      for (int d = 0; d < NDIR; ++d) a[d] = actA(d, kt);
      #pragma unroll
      for (int nt = 0; nt < 8; ++nt) {
        half8 bq = *reinterpret_cast<const half8*>(&bstage[cur][nt * 512 + lane * 8]);
        #pragma unroll
        for (int d = 0; d < NDIR; ++d) acc[d][nt] = mfma16(a[d], bq, acc[d][nt]);
      }
      if (!(layer == 2 && kt == 3)) {  // last slab: no one reuses bstage
        __syncthreads();
        cur ^= 1;
      }
    }
    if (layer == 1) {
      #pragma unroll
      for (int d = 0; d < NDIR; ++d) store_act(d, b1);
    }
  }

  // ================= epilogue: bias+relu(+pool), heads ===================
  f32x4 y[8];
  #pragma unroll
  for (int nt = 0; nt < 8; ++nt) {
    float bv = b2[nt * 16 + lrow];
    #pragma unroll
    for (int r = 0; r < 4; ++r) {
      float v = fmaxf(acc[0][nt][r] + bv, 0.f);
      if constexpr (NDIR == 2) v += fmaxf(acc[1][nt][r] + bv, 0.f);
      y[nt][r] = v;
    }
  }

  const float* hws[3] = {hw0, hw1, hw2};
  const float* hbs[3] = {hb0, hb1, hb2};
  float* outs[3] = {out0, out1, out2};
  #pragma unroll
  for (int hd = 0; hd < NHEAD; ++hd) {
    float p[4] = {0.f, 0.f, 0.f, 0.f};
    #pragma unroll
    for (int nt = 0; nt < 8; ++nt) {
      float w = hws[hd][nt * 16 + lrow];
      #pragma unroll
      for (int r = 0; r < 4; ++r) p[r] += y[nt][r] * w;
    }
    #pragma unroll
    for (int m = 1; m < 16; m <<= 1) {
      #pragma unroll
      for (int r = 0; r < 4; ++r) p[r] += __shfl_xor(p[r], m, 64);
    }
    if (wr && lrow < 4) {
      float pv = (lrow == 0) ? p[0] : (lrow == 1) ? p[1] : (lrow == 2) ? p[2] : p[3];
      outs[hd][tile * 16 + 4 * kb + lrow] = pv + hbs[hd][0];
    }
  }
}

// -------------------------------------------------------------------------
extern "C" void kernel_launch(void* const* d_in, const int* in_sizes, int n_in,
                              void* d_out, int out_size, void* d_ws, size_t ws_size,
                              hipStream_t stream) {
  (void)in_sizes; (void)n_in; (void)out_size;

  const float* h = (const float*)d_in[0];
  const int* idx2 = (const int*)d_in[1];
  const int* idx3 = (const int*)d_in[2];
  const int* idx4 = (const int*)d_in[3];

  const float* sW[4][3];
  const float* sb[4][3];
  for (int L = 0; L < 4; ++L)
    for (int j = 0; j < 3; ++j) {
      sW[L][j] = (const float*)d_in[4 + L * 6 + j * 2];
      sb[L][j] = (const float*)d_in[4 + L * 6 + j * 2 + 1];
    }
  // heads: h1_sigma, h1_epsilon, h1_q, h2_k, h2_eq, h3_k, h3_eq, h4_k, h4_eq
  const float* hW[9];
  const float* hB[9];
  for (int i = 0; i < 9; ++i) {
    hW[i] = (const float*)d_in[28 + i * 2];
    hB[i] = (const float*)d_in[28 + i * 2 + 1];
  }

  // workspace: fp16 h (12.8M elems) + packed weights (294912 elems)
  size_t need = ((size_t)N1_ * 128 + 294912) * 2;
  if (ws_size < need) return;
  unsigned short* hf = (unsigned short*)d_ws;
  unsigned short* pw = hf + (size_t)N1_ * 128;

  cvt_h_kernel<<<(N1_ * 128 / 4 + 255) / 256, 256, 0, stream>>>(h, hf, N1_ * 128 / 4);

  PackInfo pi;
  const int din[12] = {128, 128, 128, 256, 128, 128, 384, 128, 128, 512, 128, 128};
  int ktb = 0, ooff = 0;
  for (int m = 0; m < 12; ++m) {
    pi.W[m] = sW[m / 3][m % 3];
    pi.kt_base[m] = ktb;
    pi.out_off[m] = ooff;
    ktb += din[m] / 32;
    ooff += din[m] * 128;
  }
  pi.kt_base[12] = ktb;  // 72
  pack_w_kernel<<<ktb, 64, 0, stream>>>(pi, pw);

  float* out = (float*)d_out;
  float* o_sigma = out;
  float* o_eps = out + N1_;
  float* o_q = out + 2 * N1_;
  float* o_k2 = out + 3 * N1_;
  float* o_eq2 = o_k2 + N2_;
  float* o_k3 = o_eq2 + N2_;
  float* o_eq3 = o_k3 + N3_;
  float* o_k4 = o_eq3 + N3_;
  float* o_eq4 = o_k4 + N4_;

  // grid: each block covers 8 waves x 1 tile = 128 rows
  level_kernel<1, 3><<<(N1_ / 16 + 7) / 8, 512, 0, stream>>>(
      hf, nullptr, pw + pi.out_off[0], sb[0][0], sb[0][1], sb[0][2],
      hW[0], hB[0], o_sigma, hW[1], hB[1], o_eps, hW[2], hB[2], o_q, N1_);
  level_kernel<2, 2><<<(N2_ / 16 + 7) / 8, 512, 0, stream>>>(
      hf, idx2, pw + pi.out_off[3], sb[1][0], sb[1][1], sb[1][2],
      hW[3], hB[3], o_k2, hW[4], hB[4], o_eq2, nullptr, nullptr, nullptr, N2_);
  level_kernel<3, 2><<<(N3_ / 16 + 7) / 8, 512, 0, stream>>>(
      hf, idx3, pw + pi.out_off[6], sb[2][0], sb[2][1], sb[2][2],
      hW[5], hB[5], o_k3, hW[6], hB[6], o_eq3, nullptr, nullptr, nullptr, N3_);
  level_kernel<4, 2><<<(N4_ / 16 + 7) / 8, 512, 0, stream>>>(
      hf, idx4, pw + pi.out_off[9], sb[3][0], sb[3][1], sb[3][2],
      hW[7], hB[7], o_k4, hW[8], hB[8], o_eq4, nullptr, nullptr, nullptr, N4_);
}

// Round 6
// 442.627 us; speedup vs baseline: 1.3329x; 1.3329x over previous
//
#include <hip/hip_runtime.h>

typedef __attribute__((ext_vector_type(8))) _Float16 half8;
typedef __attribute__((ext_vector_type(4))) float f32x4;

#define N1_ 100000
#define N2_ 200000
#define N3_ 300000
#define N4_ 400000

typedef __attribute__((address_space(1))) const void gconst_t;
typedef __attribute__((address_space(3))) void lds_t;

__device__ __forceinline__ unsigned short f2h_bits(float x) {
  union { _Float16 h; unsigned short u; } cv;
  cv.h = (_Float16)x;
  return cv.u;
}

__device__ __forceinline__ f32x4 mfma16(half8 a, half8 b, f32x4 c) {
  return __builtin_amdgcn_mfma_f32_16x16x32_f16(a, b, c, 0, 0, 0);
}

// ---- convert h (fp32) -> fp16 bits --------------------------------------
__global__ void cvt_h_kernel(const float* __restrict__ h,
                             unsigned short* __restrict__ hf, int n4) {
  int i = blockIdx.x * blockDim.x + threadIdx.x;
  if (i >= n4) return;
  float4 v = reinterpret_cast<const float4*>(h)[i];
  ushort4 o;
  o.x = f2h_bits(v.x); o.y = f2h_bits(v.y);
  o.z = f2h_bits(v.z); o.w = f2h_bits(v.w);
  reinterpret_cast<ushort4*>(hf)[i] = o;
}

// ---- pack weights into MFMA B-fragment order ----------------------------
// packed[kt*4096 + nt*512 + lane*8 + j] = W[kt*32 + (lane>>4)*8 + j][nt*16 + (lane&15)]
struct PackInfo {
  const float* W[12];
  int kt_base[13];
  int out_off[12];
};

__global__ void pack_w_kernel(PackInfo info, unsigned short* __restrict__ pw) {
  int b = blockIdx.x;
  int lane = threadIdx.x;  // 64 threads
  int m = 0;
  while (m < 11 && b >= info.kt_base[m + 1]) ++m;
  int kt = b - info.kt_base[m];
  const float* W = info.W[m];
  int lr = lane & 15, kb = lane >> 4;
  unsigned short* outp = pw + info.out_off[m] + (size_t)kt * 4096 + lane * 8;
  #pragma unroll
  for (int nt = 0; nt < 8; ++nt) {
    #pragma unroll
    for (int j = 0; j < 8; ++j) {
      int krow = kt * 32 + kb * 8 + j;
      int col = nt * 16 + lr;
      outp[nt * 512 + j] = f2h_bits(W[(size_t)krow * 128 + col]);
    }
  }
}

// ---- main level kernel --------------------------------------------------
// 4 waves/block x ONE 16-row tile each. 2-phase staged weight slabs (8 KB,
// each wave DMAs 2 KB). Paired-gather layer-0 stream (fwd/bwd share each
// gathered fragment pair). 48 KB LDS -> 3 blocks/CU = 12 waves/CU; acc =
// 64 f32 (1 tile x 2 dir) fits the 3-waves/SIMD register budget (~170).
template <int K, int NHEAD>
__global__ __launch_bounds__(256, (K == 1) ? 4 : 3) void level_kernel(
    const unsigned short* __restrict__ hf,
    const int* __restrict__ idx,
    const unsigned short* __restrict__ pw,  // packed W0|W1|W2 (fp16 bits)
    const float* __restrict__ b0, const float* __restrict__ b1,
    const float* __restrict__ b2,
    const float* __restrict__ hw0, const float* __restrict__ hb0,
    float* __restrict__ out0,
    const float* __restrict__ hw1, const float* __restrict__ hb1,
    float* __restrict__ out1,
    const float* __restrict__ hw2, const float* __restrict__ hb2,
    float* __restrict__ out2,
    int N) {
  constexpr int NDIR = (K > 1) ? 2 : 1;
  constexpr int KT0 = 4 * K;
  constexpr int NPAIR = (K / 2) * 4;   // paired phases = 2*NPAIR
  constexpr bool MID = (K % 2) != 0;   // middle seg (odd K, incl. K==1)

  __shared__ __align__(16) unsigned short bstage[2][4096];     // 16 KB
  __shared__ __align__(16) unsigned short act[4][NDIR][2048];  // 16/32 KB

  const int lane = threadIdx.x & 63;
  const int wid = threadIdx.x >> 6;   // 0..3
  const int lrow = lane & 15;
  const int kb = lane >> 4;

  int tile = blockIdx.x * 4 + wid;
  const int maxtile = N / 16 - 1;
  const bool wr = (tile <= maxtile);
  if (!wr) tile = maxtile;  // clamp: all waves hit barriers, only writers store

  int src[K];
  #pragma unroll
  for (int s = 0; s < K; ++s)
    src[s] = (K == 1) ? (tile * 16 + lrow)
                      : idx[(size_t)(tile * 16 + lrow) * K + s];

  // stage one 8 KB slab into bstage[buf]; each wave DMAs 2x1KB, width-16
  auto stage = [&](int buf, const unsigned short* slab) {
    const unsigned short* g = slab + (wid * 2) * 512 + lane * 8;
    unsigned short* l = &bstage[buf][(wid * 2) * 512];
    __builtin_amdgcn_global_load_lds((gconst_t*)g, (lds_t*)l, 16, 0, 0);
    __builtin_amdgcn_global_load_lds((gconst_t*)(g + 512), (lds_t*)(l + 512), 16, 0, 0);
  };

  // gathered fragment for (segRow, sub): 16B/lane from h-row src[segRow]
  auto gfrag = [&](int segRow, int sub, half8& dst) {
    dst = *reinterpret_cast<const half8*>(
        hf + (size_t)src[segRow] * 128 + sub * 32 + kb * 8);
  };

  f32x4 acc[NDIR][8];
  auto zero_acc = [&]() {
    #pragma unroll
    for (int d = 0; d < NDIR; ++d)
      #pragma unroll
      for (int nt = 0; nt < 8; ++nt) acc[d][nt] = f32x4{0.f, 0.f, 0.f, 0.f};
  };

  // one slab's MFMAs: acc[0] uses af, acc[1] uses ab (weights in bstage[buf])
  auto mfma_phase = [&](int buf, half8 af, half8 ab) {
    #pragma unroll
    for (int nt = 0; nt < 8; ++nt) {
      half8 bq = *reinterpret_cast<const half8*>(&bstage[buf][nt * 512 + lane * 8]);
      acc[0][nt] = mfma16(af, bq, acc[0][nt]);
      if constexpr (NDIR == 2) acc[1][nt] = mfma16(ab, bq, acc[1][nt]);
    }
  };

  // layers 1/2: A from per-wave activation LDS (XOR-swizzled rows)
  auto actA = [&](int d, int kt) -> half8 {
    unsigned off = (unsigned)(lrow * 256 + (kt * 32 + kb * 8) * 2) ^
                   ((unsigned)(lrow & 7) << 4);
    return *reinterpret_cast<const half8*>(
        reinterpret_cast<const unsigned char*>(&act[wid][d][0]) + off);
  };

  // bias + relu + fp16 store to swizzled act LDS (D-frag: row=4*kb+r, col=nt*16+lrow)
  auto store_act = [&](int d, const float* bias) {
    unsigned char* base = reinterpret_cast<unsigned char*>(&act[wid][d][0]);
    #pragma unroll
    for (int nt = 0; nt < 8; ++nt) {
      float bv = bias[nt * 16 + lrow];
      #pragma unroll
      for (int r = 0; r < 4; ++r) {
        float v = fmaxf(acc[d][nt][r] + bv, 0.f);
        int trow = 4 * kb + r;
        unsigned off = (unsigned)(trow * 256 + (nt * 16 + lrow) * 2) ^
                       ((unsigned)(trow & 7) << 4);
        *reinterpret_cast<unsigned short*>(base + off) = f2h_bits(v);
      }
    }
  };

  int cur = 0;
  zero_acc();

  // ================= layer 0: paired-gather slab stream ===================
  half8 gA, gB, nA, nB;
  stage(cur, pw);        // first slab: pair0 slabA, or mid slab 0 (K==1)
  gfrag(0, 0, gA);
  if constexpr (NPAIR > 0) gfrag(K - 1, 0, gB);
  __syncthreads();

  for (int pr = 0; pr < NPAIR; ++pr) {
    const int sp = pr >> 2, sub = pr & 3;
    const int slabB = (K - 1 - sp) * 4 + sub;
    // -- phase 1: weights slab (sp,sub): fwd uses gA, bwd uses gB
    stage(cur ^ 1, pw + (size_t)slabB * 4096);
    mfma_phase(cur, gA, gB);
    __syncthreads();
    cur ^= 1;
    // -- phase 2: weights slab (K-1-sp,sub): fwd uses gB, bwd uses gA
    if (pr + 1 < NPAIR) {
      const int sp2 = (pr + 1) >> 2, sub2 = (pr + 1) & 3;
      stage(cur ^ 1, pw + (size_t)(sp2 * 4 + sub2) * 4096);
      gfrag(sp2, sub2, nA);
      gfrag(K - 1 - sp2, sub2, nB);
    } else if constexpr (MID) {
      stage(cur ^ 1, pw + (size_t)(((K - 1) / 2) * 4) * 4096);
      gfrag((K - 1) / 2, 0, nA);
    } else {
      stage(cur ^ 1, pw + (size_t)KT0 * 4096);  // layer-1 slab 0
    }
    mfma_phase(cur, gB, gA);
    __syncthreads();
    cur ^= 1;
    gA = nA; gB = nB;
  }

  if constexpr (MID) {
    const int mseg = (K - 1) / 2;
    for (int sub = 0; sub < 4; ++sub) {
      if (sub + 1 < 4) {
        stage(cur ^ 1, pw + (size_t)(mseg * 4 + sub + 1) * 4096);
        gfrag(mseg, sub + 1, nA);
      } else {
        stage(cur ^ 1, pw + (size_t)KT0 * 4096);  // layer-1 slab 0
      }
      mfma_phase(cur, gA, gA);  // fwd and bwd share the middle fragment
      __syncthreads();
      cur ^= 1;
      gA = nA;
    }
  }

  #pragma unroll
  for (int d = 0; d < NDIR; ++d) store_act(d, b0);

  // ================= layers 1 and 2 (A from act LDS) =====================
  const unsigned short* w1 = pw + (size_t)KT0 * 4096;
  #pragma unroll 1
  for (int layer = 1; layer <= 2; ++layer) {
    const unsigned short* w = (layer == 1) ? w1 : w1 + 16384;
    zero_acc();
    for (int kt = 0; kt < 4; ++kt) {
      if (kt + 1 < 4) stage(cur ^ 1, w + (size_t)(kt + 1) * 4096);
      else if (layer == 1) stage(cur ^ 1, w1 + 16384);  // layer-2 slab 0
      half8 a[NDIR];
      #pragma unroll
      for (int d = 0; d < NDIR; ++d) a[d] = actA(d, kt);
      #pragma unroll
      for (int nt = 0; nt < 8; ++nt) {
        half8 bq = *reinterpret_cast<const half8*>(&bstage[cur][nt * 512 + lane * 8]);
        #pragma unroll
        for (int d = 0; d < NDIR; ++d) acc[d][nt] = mfma16(a[d], bq, acc[d][nt]);
      }
      if (!(layer == 2 && kt == 3)) {  // last slab: no one reuses bstage
        __syncthreads();
        cur ^= 1;
      }
    }
    if (layer == 1) {
      #pragma unroll
      for (int d = 0; d < NDIR; ++d) store_act(d, b1);
    }
  }

  // ================= epilogue: bias+relu(+pool), heads ===================
  f32x4 y[8];
  #pragma unroll
  for (int nt = 0; nt < 8; ++nt) {
    float bv = b2[nt * 16 + lrow];
    #pragma unroll
    for (int r = 0; r < 4; ++r) {
      float v = fmaxf(acc[0][nt][r] + bv, 0.f);
      if constexpr (NDIR == 2) v += fmaxf(acc[1][nt][r] + bv, 0.f);
      y[nt][r] = v;
    }
  }

  const float* hws[3] = {hw0, hw1, hw2};
  const float* hbs[3] = {hb0, hb1, hb2};
  float* outs[3] = {out0, out1, out2};
  #pragma unroll
  for (int hd = 0; hd < NHEAD; ++hd) {
    float p[4] = {0.f, 0.f, 0.f, 0.f};
    #pragma unroll
    for (int nt = 0; nt < 8; ++nt) {
      float w = hws[hd][nt * 16 + lrow];
      #pragma unroll
      for (int r = 0; r < 4; ++r) p[r] += y[nt][r] * w;
    }
    #pragma unroll
    for (int m = 1; m < 16; m <<= 1) {
      #pragma unroll
      for (int r = 0; r < 4; ++r) p[r] += __shfl_xor(p[r], m, 64);
    }
    if (wr && lrow < 4) {
      float pv = (lrow == 0) ? p[0] : (lrow == 1) ? p[1] : (lrow == 2) ? p[2] : p[3];
      outs[hd][tile * 16 + 4 * kb + lrow] = pv + hbs[hd][0];
    }
  }
}

// -------------------------------------------------------------------------
extern "C" void kernel_launch(void* const* d_in, const int* in_sizes, int n_in,
                              void* d_out, int out_size, void* d_ws, size_t ws_size,
                              hipStream_t stream) {
  (void)in_sizes; (void)n_in; (void)out_size;

  const float* h = (const float*)d_in[0];
  const int* idx2 = (const int*)d_in[1];
  const int* idx3 = (const int*)d_in[2];
  const int* idx4 = (const int*)d_in[3];

  const float* sW[4][3];
  const float* sb[4][3];
  for (int L = 0; L < 4; ++L)
    for (int j = 0; j < 3; ++j) {
      sW[L][j] = (const float*)d_in[4 + L * 6 + j * 2];
      sb[L][j] = (const float*)d_in[4 + L * 6 + j * 2 + 1];
    }
  // heads: h1_sigma, h1_epsilon, h1_q, h2_k, h2_eq, h3_k, h3_eq, h4_k, h4_eq
  const float* hW[9];
  const float* hB[9];
  for (int i = 0; i < 9; ++i) {
    hW[i] = (const float*)d_in[28 + i * 2];
    hB[i] = (const float*)d_in[28 + i * 2 + 1];
  }

  // workspace: fp16 h (12.8M elems) + packed weights (294912 elems)
  size_t need = ((size_t)N1_ * 128 + 294912) * 2;
  if (ws_size < need) return;
  unsigned short* hf = (unsigned short*)d_ws;
  unsigned short* pw = hf + (size_t)N1_ * 128;

  cvt_h_kernel<<<(N1_ * 128 / 4 + 255) / 256, 256, 0, stream>>>(h, hf, N1_ * 128 / 4);

  PackInfo pi;
  const int din[12] = {128, 128, 128, 256, 128, 128, 384, 128, 128, 512, 128, 128};
  int ktb = 0, ooff = 0;
  for (int m = 0; m < 12; ++m) {
    pi.W[m] = sW[m / 3][m % 3];
    pi.kt_base[m] = ktb;
    pi.out_off[m] = ooff;
    ktb += din[m] / 32;
    ooff += din[m] * 128;
  }
  pi.kt_base[12] = ktb;  // 72
  pack_w_kernel<<<ktb, 64, 0, stream>>>(pi, pw);

  float* out = (float*)d_out;
  float* o_sigma = out;
  float* o_eps = out + N1_;
  float* o_q = out + 2 * N1_;
  float* o_k2 = out + 3 * N1_;
  float* o_eq2 = o_k2 + N2_;
  float* o_k3 = o_eq2 + N2_;
  float* o_eq3 = o_k3 + N3_;
  float* o_k4 = o_eq3 + N3_;
  float* o_eq4 = o_k4 + N4_;

  // grid: each block covers 4 waves x 1 tile = 64 rows
  level_kernel<1, 3><<<(N1_ / 16 + 3) / 4, 256, 0, stream>>>(
      hf, nullptr, pw + pi.out_off[0], sb[0][0], sb[0][1], sb[0][2],
      hW[0], hB[0], o_sigma, hW[1], hB[1], o_eps, hW[2], hB[2], o_q, N1_);
  level_kernel<2, 2><<<(N2_ / 16 + 3) / 4, 256, 0, stream>>>(
      hf, idx2, pw + pi.out_off[3], sb[1][0], sb[1][1], sb[1][2],
      hW[3], hB[3], o_k2, hW[4], hB[4], o_eq2, nullptr, nullptr, nullptr, N2_);
  level_kernel<3, 2><<<(N3_ / 16 + 3) / 4, 256, 0, stream>>>(
      hf, idx3, pw + pi.out_off[6], sb[2][0], sb[2][1], sb[2][2],
      hW[5], hB[5], o_k3, hW[6], hB[6], o_eq3, nullptr, nullptr, nullptr, N3_);
  level_kernel<4, 2><<<(N4_ / 16 + 3) / 4, 256, 0, stream>>>(
      hf, idx4, pw + pi.out_off[9], sb[3][0], sb[3][1], sb[3][2],
      hW[7], hB[7], o_k4, hW[8], hB[8], o_eq4, nullptr, nullptr, nullptr, N4_);
}